// Round 2
// baseline (327.508 us; speedup 1.0000x reference)
//
#include <hip/hip_runtime.h>

#define NN 3072
#define FIN 1546
#define KP 1568          // FIN padded to multiple of 32
#define MAXR 192         // max CSR nnz/row (measured mean ~61)

#define XS4_BLOCKS (NN * KP / 1024)        // 4704  (4 elems/thread)
#define WSPLIT_BLOCKS (256 * KP / 256)     // 1568
#define WG_BLOCKS 704                       // 384 WgaT + 192 WgbT + 128 WaT
#define CSR_BLOCKS (NN / 4)                // 768
#define FC1_BLOCKS (NN / 16)               // 192 fc1 row-tiles in fused fc1+mask dispatch

typedef __attribute__((ext_vector_type(8))) __bf16 bf16x8;
typedef __attribute__((ext_vector_type(4))) __bf16 bf16x4;
typedef __attribute__((ext_vector_type(4))) float f32x4;

// ---- fused prep: xsplit x4 ; wsplit ; Wg/Wa transpose+split ; csr (float4+ballot4) ----
__global__ __launch_bounds__(256) void prep_k(const float* __restrict__ adj,
                                              int* __restrict__ cols, float* __restrict__ vals,
                                              int* __restrict__ cnt, float* __restrict__ dvec,
                                              const float* __restrict__ X,
                                              __bf16* __restrict__ Xh, __bf16* __restrict__ Xl,
                                              const float* __restrict__ W,
                                              __bf16* __restrict__ WhT, __bf16* __restrict__ WlT,
                                              const float* __restrict__ Wga0,
                                              const float* __restrict__ Wga1,
                                              const float* __restrict__ Wga2,
                                              const float* __restrict__ Wgb0,
                                              const float* __restrict__ Wgb1,
                                              const float* __restrict__ Wgb2,
                                              const float* __restrict__ Wa,
                                              __bf16* __restrict__ WgaTh, __bf16* __restrict__ WgaTl,
                                              __bf16* __restrict__ WgbTh, __bf16* __restrict__ WgbTl,
                                              __bf16* __restrict__ WaTh, __bf16* __restrict__ WaTl) {
    int bid = blockIdx.x;
    if (bid < XS4_BLOCKS) {
        int e = (bid * 256 + threadIdx.x) * 4;        // 4 elems, same row (KP%4==0)
        int i = e / KP, c = e - i * KP;
        const float* xr = X + (size_t)i * FIN + c;
        float x0 = (c + 0 < FIN) ? xr[0] : 0.f;
        float x1 = (c + 1 < FIN) ? xr[1] : 0.f;
        float x2 = (c + 2 < FIN) ? xr[2] : 0.f;
        float x3 = (c + 3 < FIN) ? xr[3] : 0.f;
        __bf16 h0 = (__bf16)x0, h1 = (__bf16)x1, h2 = (__bf16)x2, h3 = (__bf16)x3;
        bf16x4 hv = {h0, h1, h2, h3};
        bf16x4 lv = {(__bf16)(x0 - (float)h0), (__bf16)(x1 - (float)h1),
                     (__bf16)(x2 - (float)h2), (__bf16)(x3 - (float)h3)};
        *(bf16x4*)(Xh + e) = hv;
        *(bf16x4*)(Xl + e) = lv;
        return;
    }
    bid -= XS4_BLOCKS;
    if (bid < WSPLIT_BLOCKS) {
        int idx = bid * 256 + threadIdx.x;
        int c = idx / KP, k = idx - c * KP;
        float x = (k < FIN) ? W[(size_t)k * 256 + c] : 0.f;
        __bf16 h = (__bf16)x;
        WhT[idx] = h;
        WlT[idx] = (__bf16)(x - (float)h);
        return;
    }
    bid -= WSPLIT_BLOCKS;
    if (bid < WG_BLOCKS) {
        // transpose + h/l split of the small GCN / pair-MLP weights for MFMA B-operands
        int idx = bid * 256 + threadIdx.x;
        float x;
        __bf16 *oh, *ol;
        int off;
        if (idx < 98304) {                      // WgaT[b][c][k]: [3][128][256]
            int b = idx >> 15, r = idx & 32767;
            int c = r >> 8, k = r & 255;
            const float* Wp = (b == 0) ? Wga0 : (b == 1) ? Wga1 : Wga2;
            x = Wp[k * 128 + c];                // Wga: [256][128]
            oh = WgaTh; ol = WgaTl; off = idx;
        } else if (idx < 98304 + 49152) {       // WgbT[b][c][k]: [3][128][128]
            int j = idx - 98304;
            int b = j >> 14, r = j & 16383;
            int c = r >> 7, k = r & 127;
            const float* Wp = (b == 0) ? Wgb0 : (b == 1) ? Wgb1 : Wgb2;
            x = Wp[k * 128 + c];                // Wgb: [128][128]
            oh = WgbTh; ol = WgbTl; off = j;
        } else {                                // WaT[c][k]: [128][256], c<64 left, c>=64 right
            int j = idx - 147456;
            int c = j >> 8, k = j & 255;
            x = (c < 64) ? Wa[(size_t)k * 64 + c] : Wa[(size_t)(256 + k) * 64 + (c - 64)];
            oh = WaTh; ol = WaTl; off = j;
        }
        __bf16 h = (__bf16)x;
        oh[off] = h;
        ol[off] = (__bf16)(x - (float)h);
        return;
    }
    bid -= WG_BLOCKS;
    int i = bid * 4 + (threadIdx.x >> 6);
    int lane = threadIdx.x & 63;
    const float* row = adj + (size_t)i * NN;
    unsigned long long below = (1ull << lane) - 1ull;
    float s = 0.f; int count = 0;
    int base = i * MAXR;
    for (int c0 = 0; c0 < NN; c0 += 256) {
        float4 a4 = *(const float4*)(row + c0 + lane * 4);
        float a[4] = {a4.x, a4.y, a4.z, a4.w};
        s += a[0] + a[1] + a[2] + a[3];
        unsigned long long bal[4];
        #pragma unroll
        for (int u = 0; u < 4; u++) bal[u] = __ballot(a[u] != 0.f);
        int before = 0;
        #pragma unroll
        for (int u = 0; u < 4; u++) before += __popcll(bal[u] & below);
        int local = 0;
        #pragma unroll
        for (int u = 0; u < 4; u++) {
            if (a[u] != 0.f) {
                int pos = count + before + local;
                if (pos < MAXR) { cols[base + pos] = c0 + lane * 4 + u; vals[base + pos] = a[u]; }
                local++;
            }
        }
        int tot = 0;
        #pragma unroll
        for (int u = 0; u < 4; u++) tot += __popcll(bal[u]);
        count += tot;
    }
    for (int off = 32; off; off >>= 1) s += __shfl_xor(s, off);
    if (lane == 0) {
        cnt[i] = count < MAXR ? count : MAXR;
        dvec[i] = (s > 0.f) ? 1.0f / sqrtf(s) : 0.f;
    }
}

// ---- fused: fc1 MFMA (full-K, M=16 tiles, direct X0 h/l out) + threshold masks ----
// block order: [0,192) fc1 (critical path for gemm1); [192,+NN) mode2 heavy An^2;
// then mode0, mode1 light masks.
__global__ __launch_bounds__(256) void fc1mask_k(const int* __restrict__ cols,
                                                 const float* __restrict__ vals,
                                                 const int* __restrict__ cnt,
                                                 const float* __restrict__ dvec,
                                                 const float* __restrict__ thrp,
                                                 int* __restrict__ mcols,
                                                 float* __restrict__ mvals,
                                                 int* __restrict__ mcnt,
                                                 float* __restrict__ db,
                                                 const __bf16* __restrict__ Xh,
                                                 const __bf16* __restrict__ Xl,
                                                 const __bf16* __restrict__ WhT,
                                                 const __bf16* __restrict__ WlT,
                                                 const float* __restrict__ bias,
                                                 __bf16* __restrict__ X0h,
                                                 __bf16* __restrict__ X0l) {
    __shared__ float ds[NN];
    __shared__ int lcols[MAXR];
    __shared__ float lvals[MAXR];
    __shared__ int lcnt;
    __shared__ float osum;
    int bid = blockIdx.x, tid = threadIdx.x;

    if (bid < FC1_BLOCKS) {
        // fc1: 16-row tile, 4 waves x 64 cols, full K=1568, split-bf16 3-term MFMA
        int w = tid >> 6, lane = tid & 63;
        int m = lane & 15, q = lane >> 4;
        int r0 = bid * 16;
        int rowA = r0 + m;
        const __bf16* xh = Xh + (size_t)rowA * KP + q * 8;
        const __bf16* xl = Xl + (size_t)rowA * KP + q * 8;
        int c0 = w * 64;
        const __bf16* bh0 = WhT + (size_t)(c0 + m) * KP + q * 8;
        const __bf16* bl0 = WlT + (size_t)(c0 + m) * KP + q * 8;

        f32x4 acc[4];
        #pragma unroll
        for (int ct = 0; ct < 4; ct++)
            #pragma unroll
            for (int r = 0; r < 4; r++) acc[ct][r] = 0.f;

        for (int ks = 0; ks < KP; ks += 32) {
            bf16x8 ah = *(const bf16x8*)(xh + ks);
            bf16x8 al = *(const bf16x8*)(xl + ks);
            #pragma unroll
            for (int ct = 0; ct < 4; ct++) {
                bf16x8 bh = *(const bf16x8*)(bh0 + (size_t)ct * 16 * KP + ks);
                bf16x8 bl = *(const bf16x8*)(bl0 + (size_t)ct * 16 * KP + ks);
                acc[ct] = __builtin_amdgcn_mfma_f32_16x16x32_bf16(ah, bh, acc[ct], 0, 0, 0);
                acc[ct] = __builtin_amdgcn_mfma_f32_16x16x32_bf16(ah, bl, acc[ct], 0, 0, 0);
                acc[ct] = __builtin_amdgcn_mfma_f32_16x16x32_bf16(al, bh, acc[ct], 0, 0, 0);
            }
        }
        #pragma unroll
        for (int ct = 0; ct < 4; ct++) {
            int col = c0 + ct * 16 + m;
            float bv = bias[col];
            #pragma unroll
            for (int r = 0; r < 4; r++) {
                int row = r0 + q * 4 + r;
                float s = fmaxf(acc[ct][r] + bv, 0.f);
                __bf16 h = (__bf16)s;
                X0h[(size_t)row * 256 + col] = h;
                X0l[(size_t)row * 256 + col] = (__bf16)(s - (float)h);
            }
        }
        return;
    }

    int t = bid - FC1_BLOCKS;
    int mode, i;
    if (t < NN)          { mode = 2; i = t; }
    else if (t < 2 * NN) { mode = 0; i = t - NN; }
    else                 { mode = 1; i = t - 2 * NN; }

    mcols += (size_t)mode * NN * MAXR;
    mvals += (size_t)mode * NN * MAXR;
    mcnt  += (size_t)mode * NN;
    db    += (size_t)mode * NN;
    int ni = cnt[i], base = i * MAXR;
    float thr = *thrp;
    float di = dvec[i];

    if (mode < 2) {
        if (tid == 0) lcnt = 0;
        __syncthreads();
        float s = 0.f;
        if (tid < ni) {
            int j = cols[base + tid];
            float a = vals[base + tid];
            float m = (mode == 0) ? a : a * di * dvec[j];
            if (m > thr) {
                int p = atomicAdd(&lcnt, 1);
                mcols[base + p] = j;
                mvals[base + p] = a;
                s = a;
            }
        }
        ds[tid] = s; __syncthreads();
        for (int off = 128; off; off >>= 1) {
            if (tid < off) ds[tid] += ds[tid + off];
            __syncthreads();
        }
        if (tid == 0) {
            mcnt[i] = lcnt;
            db[i] = 1.0f / sqrtf(ds[0] + 1.0f);
        }
        return;
    }

    if (tid == 0) { osum = 0.f; lcnt = 0; }
    for (int j = tid; j < NN; j += 256) ds[j] = 0.f;
    __syncthreads();
    for (int t2 = tid; t2 < ni; t2 += 256) {
        int j = cols[base + t2];
        float a = vals[base + t2];
        lcols[t2] = j; lvals[t2] = a;
        ds[j] = a * dvec[j] * dvec[j];
    }
    __syncthreads();
    int lane = tid & 63, wv = tid >> 6;
    int sub = lane & 15, dg = lane >> 4;      // 16-lane subgroup, 4 dots/wave in flight
    for (int o = wv * 4 + dg; o < ni; o += 16) {
        int j = lcols[o];
        int nj = cnt[j], bj = j * MAXR;
        float dot = 0.f;
        for (int t2 = sub; t2 < nj; t2 += 16)
            dot += vals[bj + t2] * ds[cols[bj + t2]];
        #pragma unroll
        for (int off = 8; off; off >>= 1) dot += __shfl_xor(dot, off);
        if (sub == 0 && di * dvec[j] * dot > thr) {
            int p = atomicAdd(&lcnt, 1);
            mcols[base + p] = j;
            mvals[base + p] = lvals[o];
            atomicAdd(&osum, lvals[o]);
        }
    }
    __syncthreads();
    if (tid == 0) {
        mcnt[i] = lcnt;
        db[i] = 1.0f / sqrtf(osum + 1.0f);
    }
}

// ---- branch-batched MFMA GEMM (split-bf16): 64x64 tile, 4 waves; z = branch ----
__global__ __launch_bounds__(256) void gemm3m_k(const __bf16* __restrict__ Ah,
                                                const __bf16* __restrict__ Al,
                                                int aplane, int K,
                                                const __bf16* __restrict__ Bh,
                                                const __bf16* __restrict__ Bl,
                                                float* __restrict__ out) {
    int tid = threadIdx.x;
    int w = tid >> 6, lane = tid & 63;
    int m = lane & 15, q = lane >> 4;
    int i0 = blockIdx.x * 64, c0 = blockIdx.y * 64;
    int z = blockIdx.z;
    int rowA = i0 + w * 16 + m;
    const __bf16* ah = Ah + (size_t)z * aplane + (size_t)rowA * K + q * 8;
    const __bf16* al = Al + (size_t)z * aplane + (size_t)rowA * K + q * 8;
    const __bf16* bh0 = Bh + (size_t)z * 128 * K + (size_t)(c0 + m) * K + q * 8;
    const __bf16* bl0 = Bl + (size_t)z * 128 * K + (size_t)(c0 + m) * K + q * 8;

    f32x4 acc[4];
    #pragma unroll
    for (int ct = 0; ct < 4; ct++)
        #pragma unroll
        for (int r = 0; r < 4; r++) acc[ct][r] = 0.f;

    for (int ks = 0; ks < K; ks += 32) {
        bf16x8 a_h = *(const bf16x8*)(ah + ks);
        bf16x8 a_l = *(const bf16x8*)(al + ks);
        #pragma unroll
        for (int ct = 0; ct < 4; ct++) {
            bf16x8 b_h = *(const bf16x8*)(bh0 + (size_t)ct * 16 * K + ks);
            bf16x8 b_l = *(const bf16x8*)(bl0 + (size_t)ct * 16 * K + ks);
            acc[ct] = __builtin_amdgcn_mfma_f32_16x16x32_bf16(a_h, b_h, acc[ct], 0, 0, 0);
            acc[ct] = __builtin_amdgcn_mfma_f32_16x16x32_bf16(a_h, b_l, acc[ct], 0, 0, 0);
            acc[ct] = __builtin_amdgcn_mfma_f32_16x16x32_bf16(a_l, b_h, acc[ct], 0, 0, 0);
        }
    }
    float* outp = out + (size_t)z * NN * 128;
    int rowBase = i0 + w * 16 + q * 4;
    #pragma unroll
    for (int ct = 0; ct < 4; ct++) {
        int col = c0 + ct * 16 + m;
        #pragma unroll
        for (int r = 0; r < 4; r++)
            outp[(size_t)(rowBase + r) * 128 + col] = acc[ct][r];
    }
}

// ---- SpMM: masked CSR, float4 gather, 8-way t-parallel, 2-deep ILP ----
__global__ __launch_bounds__(256) void spmm3_k(const int* __restrict__ mcols,
                                               const float* __restrict__ mvals,
                                               const int* __restrict__ mcnt,
                                               const float* __restrict__ db,
                                               const float* __restrict__ Xin,   // [3][NN][128]
                                               const float* __restrict__ bias0,
                                               const float* __restrict__ bias1,
                                               const float* __restrict__ bias2,
                                               __bf16* __restrict__ outAh,      // [3][NN][128] bf16 or null
                                               __bf16* __restrict__ outAl,
                                               float* __restrict__ embf, int coff) {
    __shared__ float lcoef[MAXR];
    __shared__ int lj[MAXR];
    __shared__ float4 part[8][32];
    int i = blockIdx.x, tid = threadIdx.x, b = blockIdx.y;
    mcols += (size_t)b * NN * MAXR;
    mvals += (size_t)b * NN * MAXR;
    mcnt  += (size_t)b * NN;
    db    += (size_t)b * NN;
    const float* Xb = Xin + (size_t)b * NN * 128;
    const float* bias = (b == 0) ? bias0 : (b == 1) ? bias1 : bias2;
    float dbi = db[i];
    int n = mcnt[i], base = i * MAXR;
    if (tid < n) {
        int j = mcols[base + tid];
        lj[tid] = j;
        lcoef[tid] = mvals[base + tid] * dbi * db[j];
    }
    __syncthreads();
    int g = tid >> 5, c4 = (tid & 31) << 2;
    float4 acc = make_float4(0.f, 0.f, 0.f, 0.f);
    float4 acc2 = make_float4(0.f, 0.f, 0.f, 0.f);
    if (g == 0) {
        float4 x = *(const float4*)&Xb[(size_t)i * 128 + c4];
        float d2 = dbi * dbi;
        acc = make_float4(d2 * x.x, d2 * x.y, d2 * x.z, d2 * x.w);
    }
    int t = g;
    for (; t + 8 < n; t += 16) {
        float cf0 = lcoef[t];
        float4 x0 = *(const float4*)&Xb[(size_t)lj[t] * 128 + c4];
        float cf1 = lcoef[t + 8];
        float4 x1 = *(const float4*)&Xb[(size_t)lj[t + 8] * 128 + c4];
        acc.x += cf0 * x0.x; acc.y += cf0 * x0.y; acc.z += cf0 * x0.z; acc.w += cf0 * x0.w;
        acc2.x += cf1 * x1.x; acc2.y += cf1 * x1.y; acc2.z += cf1 * x1.z; acc2.w += cf1 * x1.w;
    }
    if (t < n) {
        float cf = lcoef[t];
        float4 x = *(const float4*)&Xb[(size_t)lj[t] * 128 + c4];
        acc.x += cf * x.x; acc.y += cf * x.y; acc.z += cf * x.z; acc.w += cf * x.w;
    }
    acc.x += acc2.x; acc.y += acc2.y; acc.z += acc2.z; acc.w += acc2.w;
    part[g][tid & 31] = acc;
    __syncthreads();
    if (tid < 32) {
        float4 s = part[0][tid];
        #pragma unroll
        for (int gg = 1; gg < 8; gg++) {
            float4 t4 = part[gg][tid];
            s.x += t4.x; s.y += t4.y; s.z += t4.z; s.w += t4.w;
        }
        int cc = tid << 2;
        float4 bv = *(const float4*)&bias[cc];
        s.x = fmaxf(s.x + bv.x, 0.f); s.y = fmaxf(s.y + bv.y, 0.f);
        s.z = fmaxf(s.z + bv.z, 0.f); s.w = fmaxf(s.w + bv.w, 0.f);
        if (outAh) {
            __bf16 h0 = (__bf16)s.x, h1 = (__bf16)s.y, h2 = (__bf16)s.z, h3 = (__bf16)s.w;
            bf16x4 hv = {h0, h1, h2, h3};
            bf16x4 lv = {(__bf16)(s.x - (float)h0), (__bf16)(s.y - (float)h1),
                         (__bf16)(s.z - (float)h2), (__bf16)(s.w - (float)h3)};
            *(bf16x4*)(outAh + ((size_t)b * NN + i) * 128 + cc) = hv;
            *(bf16x4*)(outAl + ((size_t)b * NN + i) * 128 + cc) = lv;
        }
        *(float4*)&embf[((size_t)b * NN + i) * 256 + coff + cc] = s;
    }
}

// ---- dilated 3x3 conv: LDS-staged rows + split-bf16 emb for downstream MFMA ----
__global__ __launch_bounds__(256) void conv3f_k(const float* __restrict__ emb,
                                                const float* __restrict__ ck,
                                                const float* __restrict__ cb,
                                                float* __restrict__ outf,
                                                __bf16* __restrict__ embh,
                                                __bf16* __restrict__ embl) {
    __shared__ float rows[3][3][256];
    int n = blockIdx.x, c = threadIdx.x;
    #pragma unroll
    for (int i = 0; i < 3; i++)
        #pragma unroll
        for (int kh = 0; kh < 3; kh++) {
            int nn2 = n + 2 * kh - 2;
            rows[i][kh][c] = (nn2 >= 0 && nn2 < NN) ? emb[((size_t)i * NN + nn2) * 256 + c] : 0.f;
        }
    __syncthreads();
    float s = cb[0];
    #pragma unroll
    for (int i = 0; i < 3; i++)
        #pragma unroll
        for (int kh = 0; kh < 3; kh++)
            #pragma unroll
            for (int kw = 0; kw < 3; kw++) {
                int cc = c + 2 * kw - 2;
                if (cc >= 0 && cc < 256)
                    s += rows[i][kh][cc] * ck[(i * 3 + kh) * 3 + kw];
            }
    size_t idx = (size_t)n * 256 + c;
    outf[idx] = s;
    __bf16 h = (__bf16)s;
    embh[idx] = h;
    embl[idx] = (__bf16)(s - (float)h);
}

// ---- uv GEMM (MFMA split-bf16): single plane, full K=256 ----
__global__ __launch_bounds__(256) void gemmuvm_k(const __bf16* __restrict__ Ah,
                                                 const __bf16* __restrict__ Al,
                                                 const __bf16* __restrict__ Bh,
                                                 const __bf16* __restrict__ Bl,
                                                 float* __restrict__ uvp) {
    int tid = threadIdx.x;
    int w = tid >> 6, lane = tid & 63;
    int m = lane & 15, q = lane >> 4;
    int i0 = blockIdx.x * 64, c0 = blockIdx.y * 64;
    int rowA = i0 + w * 16 + m;
    const __bf16* ah = Ah + (size_t)rowA * 256 + q * 8;
    const __bf16* al = Al + (size_t)rowA * 256 + q * 8;
    const __bf16* bh0 = Bh + (size_t)(c0 + m) * 256 + q * 8;
    const __bf16* bl0 = Bl + (size_t)(c0 + m) * 256 + q * 8;

    f32x4 acc[4];
    #pragma unroll
    for (int ct = 0; ct < 4; ct++)
        #pragma unroll
        for (int r = 0; r < 4; r++) acc[ct][r] = 0.f;

    for (int ks = 0; ks < 256; ks += 32) {
        bf16x8 a_h = *(const bf16x8*)(ah + ks);
        bf16x8 a_l = *(const bf16x8*)(al + ks);
        #pragma unroll
        for (int ct = 0; ct < 4; ct++) {
            bf16x8 b_h = *(const bf16x8*)(bh0 + (size_t)ct * 16 * 256 + ks);
            bf16x8 b_l = *(const bf16x8*)(bl0 + (size_t)ct * 16 * 256 + ks);
            acc[ct] = __builtin_amdgcn_mfma_f32_16x16x32_bf16(a_h, b_h, acc[ct], 0, 0, 0);
            acc[ct] = __builtin_amdgcn_mfma_f32_16x16x32_bf16(a_h, b_l, acc[ct], 0, 0, 0);
            acc[ct] = __builtin_amdgcn_mfma_f32_16x16x32_bf16(a_l, b_h, acc[ct], 0, 0, 0);
        }
    }
    int rowBase = i0 + w * 16 + q * 4;
    #pragma unroll
    for (int ct = 0; ct < 4; ct++) {
        int col = c0 + ct * 16 + m;
        #pragma unroll
        for (int r = 0; r < 4; r++)
            uvp[(size_t)(rowBase + r) * 128 + col] = acc[ct][r];
    }
}

// ---- pair gather + logits: 16 pairs/block, 4 per wave ----
__global__ __launch_bounds__(256) void pairuv_k(const int* __restrict__ left,
                                                const int* __restrict__ right,
                                                const float* __restrict__ uvp,
                                                const float* __restrict__ ba,
                                                const float* __restrict__ Wb,
                                                const float* __restrict__ bb,
                                                float* __restrict__ out) {
    int tid = threadIdx.x;
    int w = tid >> 6, c = tid & 63;
    int base = blockIdx.x * 16 + w * 4;
    float bac = ba[c];
    float w0 = Wb[c * 2], w1 = Wb[c * 2 + 1];
    float b0 = bb[0], b1 = bb[1];
    #pragma unroll
    for (int pp = 0; pp < 4; pp++) {
        int row = base + pp;
        int l = left[row], r = right[row];
        float h = uvp[(size_t)l * 128 + c] + uvp[(size_t)r * 128 + 64 + c] + bac;
        h = fmaxf(h, 0.f);
        float s0 = h * w0, s1 = h * w1;
        for (int off = 32; off; off >>= 1) {
            s0 += __shfl_xor(s0, off);
            s1 += __shfl_xor(s1, off);
        }
        if (c == 0) {
            out[row * 2]     = s0 + b0;
            out[row * 2 + 1] = s1 + b1;
        }
    }
}

extern "C" void kernel_launch(void* const* d_in, const int* in_sizes, int n_in,
                              void* d_out, int out_size, void* d_ws, size_t ws_size,
                              hipStream_t stream) {
    const int* left  = (const int*)d_in[0];
    const int* right = (const int*)d_in[1];
    const float* X    = (const float*)d_in[2];
    const float* adj  = (const float*)d_in[3];
    const float* thr  = (const float*)d_in[4];
    const float* Wfc1 = (const float*)d_in[5];
    const float* bfc1 = (const float*)d_in[6];
    // channel order b0,b1,b2 = (adj mask, Wg5/6), (An mask, Wg3/4), (An^2 mask, Wg1/2)
    const float* Wga[3] = { (const float*)d_in[15], (const float*)d_in[11], (const float*)d_in[7] };
    const float* bga[3] = { (const float*)d_in[16], (const float*)d_in[12], (const float*)d_in[8] };
    const float* Wgb[3] = { (const float*)d_in[17], (const float*)d_in[13], (const float*)d_in[9] };
    const float* bgb[3] = { (const float*)d_in[18], (const float*)d_in[14], (const float*)d_in[10] };
    const float* cnnk = (const float*)d_in[19];
    const float* cnnb = (const float*)d_in[20];
    const float* Wa_  = (const float*)d_in[21];
    const float* ba_  = (const float*)d_in[22];
    const float* Wb_  = (const float*)d_in[23];
    const float* bb_  = (const float*)d_in[24];

    char* p = (char*)d_ws;
    auto take = [&](size_t n) { char* q = p; p += (n + 255) & ~(size_t)255; return q; };
    float* dvec = (float*)take(NN * 4);
    float* db3  = (float*)take((size_t)3 * NN * 4);
    int*   cnt  = (int*)take(NN * 4);
    int*   mcnt3 = (int*)take((size_t)3 * NN * 4);
    int*   cols = (int*)take((size_t)NN * MAXR * 4);
    float* vals = (float*)take((size_t)NN * MAXR * 4);
    int*   mcols3 = (int*)take((size_t)3 * NN * MAXR * 4);    // 7.1 MB
    float* mvals3 = (float*)take((size_t)3 * NN * MAXR * 4);  // 7.1 MB
    __bf16* X0h  = (__bf16*)take((size_t)NN * 256 * 2);
    __bf16* X0l  = (__bf16*)take((size_t)NN * 256 * 2);
    float* XWall = (float*)take((size_t)3 * NN * 128 * 4);
    __bf16* e1h  = (__bf16*)take((size_t)3 * NN * 128 * 2);
    __bf16* e1l  = (__bf16*)take((size_t)3 * NN * 128 * 2);
    float* HW2all= (float*)take((size_t)3 * NN * 128 * 4);
    float* embf  = (float*)take((size_t)3 * NN * 256 * 4);
    __bf16* Xh   = (__bf16*)take((size_t)NN * KP * 2);        // 9.6 MB (own buffer: masks run
    __bf16* Xl   = (__bf16*)take((size_t)NN * KP * 2);        //  concurrently with fc1 now)
    __bf16* WhT  = (__bf16*)take((size_t)256 * KP * 2);       // 0.8 MB
    __bf16* WlT  = (__bf16*)take((size_t)256 * KP * 2);       // 0.8 MB
    __bf16* WgaTh = (__bf16*)take((size_t)3 * 128 * 256 * 2);
    __bf16* WgaTl = (__bf16*)take((size_t)3 * 128 * 256 * 2);
    __bf16* WgbTh = (__bf16*)take((size_t)3 * 128 * 128 * 2);
    __bf16* WgbTl = (__bf16*)take((size_t)3 * 128 * 128 * 2);
    __bf16* WaTh  = (__bf16*)take((size_t)128 * 256 * 2);
    __bf16* WaTl  = (__bf16*)take((size_t)128 * 256 * 2);
    __bf16* embh  = (__bf16*)take((size_t)NN * 256 * 2);
    __bf16* embl  = (__bf16*)take((size_t)NN * 256 * 2);
    float* uvp   = (float*)take((size_t)NN * 128 * 4);        // 1.5 MB single plane

    float* out_logits = (float*)d_out;
    float* out_emb = out_logits + 32768;

    // fused prep: xsplit + wsplit + Wg/Wa transpose-split + csr build
    prep_k<<<XS4_BLOCKS + WSPLIT_BLOCKS + WG_BLOCKS + CSR_BLOCKS, 256, 0, stream>>>(
        adj, cols, vals, cnt, dvec, X, Xh, Xl, Wfc1, WhT, WlT,
        Wga[0], Wga[1], Wga[2], Wgb[0], Wgb[1], Wgb[2], Wa_,
        WgaTh, WgaTl, WgbTh, WgbTl, WaTh, WaTl);

    // fused: fc1 direct (full-K MFMA -> X0 h/l) overlapped with all threshold masks
    fc1mask_k<<<FC1_BLOCKS + 3 * NN, 256, 0, stream>>>(cols, vals, cnt, dvec, thr,
                                                       mcols3, mvals3, mcnt3, db3,
                                                       Xh, Xl, WhT, WlT, bfc1, X0h, X0l);

    // XW[b] = X0 @ Wga[b]  (MFMA split-bf16)
    gemm3m_k<<<dim3(NN / 64, 2, 3), 256, 0, stream>>>(X0h, X0l, 0, 256, WgaTh, WgaTl, XWall);
    // e1[b] = relu(An_b @ XW[b] + bga[b]) -> e1 split-bf16 + embf cols 0..127
    spmm3_k<<<dim3(NN, 3), 256, 0, stream>>>(mcols3, mvals3, mcnt3, db3, XWall,
                                             bga[0], bga[1], bga[2], e1h, e1l, embf, 0);
    // HW2[b] = e1[b] @ Wgb[b]  (MFMA split-bf16)
    gemm3m_k<<<dim3(NN / 64, 2, 3), 256, 0, stream>>>(e1h, e1l, NN * 128, 128, WgbTh, WgbTl, HW2all);
    // e2[b] = relu(An_b @ HW2[b] + bgb[b]) -> embf cols 128..255
    spmm3_k<<<dim3(NN, 3), 256, 0, stream>>>(mcols3, mvals3, mcnt3, db3, HW2all,
                                             bgb[0], bgb[1], bgb[2], (__bf16*)0, (__bf16*)0, embf, 128);

    conv3f_k<<<NN, 256, 0, stream>>>(embf, cnnk, cnnb, out_emb, embh, embl);
    // pair MLP via u/v decomposition: uv = emb_all @ [Wa_left | Wa_right] (MFMA, full K)
    gemmuvm_k<<<dim3(NN / 64, 2), 256, 0, stream>>>(embh, embl, WaTh, WaTl, uvp);
    pairuv_k<<<16384 / 16, 256, 0, stream>>>(left, right, uvp, ba_, Wb_, bb_, out_logits);
}

// Round 3
// 303.458 us; speedup vs baseline: 1.0793x; 1.0793x over previous
//
#include <hip/hip_runtime.h>

#define NN 3072
#define FIN 1546
#define KP 1568          // FIN padded to multiple of 32
#define MAXR 192         // max CSR nnz/row (measured mean ~61)

#define XS4_BLOCKS (NN * KP / 1024)        // 4704  (4 elems/thread)
#define WSPLIT_BLOCKS (256 * KP / 256)     // 1568
#define WG_BLOCKS 704                       // 384 WgaT + 192 WgbT + 128 WaT
#define CSR_BLOCKS (NN / 4)                // 768
#define FC1_BLOCKS (NN / 16 * 4)           // 768: 192 row-tiles x 4 col-tiles

typedef __attribute__((ext_vector_type(8))) __bf16 bf16x8;
typedef __attribute__((ext_vector_type(4))) __bf16 bf16x4;
typedef __attribute__((ext_vector_type(4))) float f32x4;

// ---- fused prep: xsplit x4 ; wsplit ; Wg/Wa transpose+split ; csr (float4+ballot4) ----
__global__ __launch_bounds__(256) void prep_k(const float* __restrict__ adj,
                                              int* __restrict__ cols, float* __restrict__ vals,
                                              int* __restrict__ cnt, float* __restrict__ dvec,
                                              const float* __restrict__ X,
                                              __bf16* __restrict__ Xh, __bf16* __restrict__ Xl,
                                              const float* __restrict__ W,
                                              __bf16* __restrict__ WhT, __bf16* __restrict__ WlT,
                                              const float* __restrict__ Wga0,
                                              const float* __restrict__ Wga1,
                                              const float* __restrict__ Wga2,
                                              const float* __restrict__ Wgb0,
                                              const float* __restrict__ Wgb1,
                                              const float* __restrict__ Wgb2,
                                              const float* __restrict__ Wa,
                                              __bf16* __restrict__ WgaTh, __bf16* __restrict__ WgaTl,
                                              __bf16* __restrict__ WgbTh, __bf16* __restrict__ WgbTl,
                                              __bf16* __restrict__ WaTh, __bf16* __restrict__ WaTl) {
    int bid = blockIdx.x;
    if (bid < XS4_BLOCKS) {
        int e = (bid * 256 + threadIdx.x) * 4;        // 4 elems, same row (KP%4==0)
        int i = e / KP, c = e - i * KP;
        const float* xr = X + (size_t)i * FIN + c;
        float x0 = (c + 0 < FIN) ? xr[0] : 0.f;
        float x1 = (c + 1 < FIN) ? xr[1] : 0.f;
        float x2 = (c + 2 < FIN) ? xr[2] : 0.f;
        float x3 = (c + 3 < FIN) ? xr[3] : 0.f;
        __bf16 h0 = (__bf16)x0, h1 = (__bf16)x1, h2 = (__bf16)x2, h3 = (__bf16)x3;
        bf16x4 hv = {h0, h1, h2, h3};
        bf16x4 lv = {(__bf16)(x0 - (float)h0), (__bf16)(x1 - (float)h1),
                     (__bf16)(x2 - (float)h2), (__bf16)(x3 - (float)h3)};
        *(bf16x4*)(Xh + e) = hv;
        *(bf16x4*)(Xl + e) = lv;
        return;
    }
    bid -= XS4_BLOCKS;
    if (bid < WSPLIT_BLOCKS) {
        int idx = bid * 256 + threadIdx.x;
        int c = idx / KP, k = idx - c * KP;
        float x = (k < FIN) ? W[(size_t)k * 256 + c] : 0.f;
        __bf16 h = (__bf16)x;
        WhT[idx] = h;
        WlT[idx] = (__bf16)(x - (float)h);
        return;
    }
    bid -= WSPLIT_BLOCKS;
    if (bid < WG_BLOCKS) {
        // transpose + h/l split of the small GCN / pair-MLP weights for MFMA B-operands
        int idx = bid * 256 + threadIdx.x;
        float x;
        __bf16 *oh, *ol;
        int off;
        if (idx < 98304) {                      // WgaT[b][c][k]: [3][128][256]
            int b = idx >> 15, r = idx & 32767;
            int c = r >> 8, k = r & 255;
            const float* Wp = (b == 0) ? Wga0 : (b == 1) ? Wga1 : Wga2;
            x = Wp[k * 128 + c];                // Wga: [256][128]
            oh = WgaTh; ol = WgaTl; off = idx;
        } else if (idx < 98304 + 49152) {       // WgbT[b][c][k]: [3][128][128]
            int j = idx - 98304;
            int b = j >> 14, r = j & 16383;
            int c = r >> 7, k = r & 127;
            const float* Wp = (b == 0) ? Wgb0 : (b == 1) ? Wgb1 : Wgb2;
            x = Wp[k * 128 + c];                // Wgb: [128][128]
            oh = WgbTh; ol = WgbTl; off = j;
        } else {                                // WaT[c][k]: [128][256], c<64 left, c>=64 right
            int j = idx - 147456;
            int c = j >> 8, k = j & 255;
            x = (c < 64) ? Wa[(size_t)k * 64 + c] : Wa[(size_t)(256 + k) * 64 + (c - 64)];
            oh = WaTh; ol = WaTl; off = j;
        }
        __bf16 h = (__bf16)x;
        oh[off] = h;
        ol[off] = (__bf16)(x - (float)h);
        return;
    }
    bid -= WG_BLOCKS;
    int i = bid * 4 + (threadIdx.x >> 6);
    int lane = threadIdx.x & 63;
    const float* row = adj + (size_t)i * NN;
    unsigned long long below = (1ull << lane) - 1ull;
    float s = 0.f; int count = 0;
    int base = i * MAXR;
    for (int c0 = 0; c0 < NN; c0 += 256) {
        float4 a4 = *(const float4*)(row + c0 + lane * 4);
        float a[4] = {a4.x, a4.y, a4.z, a4.w};
        s += a[0] + a[1] + a[2] + a[3];
        unsigned long long bal[4];
        #pragma unroll
        for (int u = 0; u < 4; u++) bal[u] = __ballot(a[u] != 0.f);
        int before = 0;
        #pragma unroll
        for (int u = 0; u < 4; u++) before += __popcll(bal[u] & below);
        int local = 0;
        #pragma unroll
        for (int u = 0; u < 4; u++) {
            if (a[u] != 0.f) {
                int pos = count + before + local;
                if (pos < MAXR) { cols[base + pos] = c0 + lane * 4 + u; vals[base + pos] = a[u]; }
                local++;
            }
        }
        int tot = 0;
        #pragma unroll
        for (int u = 0; u < 4; u++) tot += __popcll(bal[u]);
        count += tot;
    }
    for (int off = 32; off; off >>= 1) s += __shfl_xor(s, off);
    if (lane == 0) {
        cnt[i] = count < MAXR ? count : MAXR;
        dvec[i] = (s > 0.f) ? 1.0f / sqrtf(s) : 0.f;
    }
}

// ---- fused: fc1 MFMA (16x64 tiles, 768 blocks, direct X0 h/l out) + threshold masks ----
// block order: [0,768) fc1 short tiles; then mode2 heavy An^2; then mode0, mode1 light.
__global__ __launch_bounds__(256) void fc1mask_k(const int* __restrict__ cols,
                                                 const float* __restrict__ vals,
                                                 const int* __restrict__ cnt,
                                                 const float* __restrict__ dvec,
                                                 const float* __restrict__ thrp,
                                                 int* __restrict__ mcols,
                                                 float* __restrict__ mvals,
                                                 int* __restrict__ mcnt,
                                                 float* __restrict__ db,
                                                 const __bf16* __restrict__ Xh,
                                                 const __bf16* __restrict__ Xl,
                                                 const __bf16* __restrict__ WhT,
                                                 const __bf16* __restrict__ WlT,
                                                 const float* __restrict__ bias,
                                                 __bf16* __restrict__ X0h,
                                                 __bf16* __restrict__ X0l) {
    __shared__ float ds[NN];
    __shared__ int lcols[MAXR];
    __shared__ float lvals[MAXR];
    __shared__ int lcnt;
    __shared__ float osum;
    int bid = blockIdx.x, tid = threadIdx.x;

    if (bid < FC1_BLOCKS) {
        // fc1: 16-row x 64-col tile; wave w owns one 16x16 full-K output fragment.
        int rt = bid >> 2;
        int c0 = (bid & 3) * 64;
        int w = tid >> 6, lane = tid & 63;
        int m = lane & 15, q = lane >> 4;
        int r0 = rt * 16;
        int cw = c0 + w * 16;
        const __bf16* xh = Xh + (size_t)(r0 + m) * KP + q * 8;
        const __bf16* xl = Xl + (size_t)(r0 + m) * KP + q * 8;
        const __bf16* bh = WhT + (size_t)(cw + m) * KP + q * 8;
        const __bf16* bl = WlT + (size_t)(cw + m) * KP + q * 8;

        f32x4 acc;
        #pragma unroll
        for (int r = 0; r < 4; r++) acc[r] = 0.f;

        #pragma unroll 7
        for (int ks = 0; ks < KP; ks += 32) {
            bf16x8 ah = *(const bf16x8*)(xh + ks);
            bf16x8 al = *(const bf16x8*)(xl + ks);
            bf16x8 bhv = *(const bf16x8*)(bh + ks);
            bf16x8 blv = *(const bf16x8*)(bl + ks);
            acc = __builtin_amdgcn_mfma_f32_16x16x32_bf16(ah, bhv, acc, 0, 0, 0);
            acc = __builtin_amdgcn_mfma_f32_16x16x32_bf16(ah, blv, acc, 0, 0, 0);
            acc = __builtin_amdgcn_mfma_f32_16x16x32_bf16(al, bhv, acc, 0, 0, 0);
        }
        int col = cw + m;
        float bv = bias[col];
        #pragma unroll
        for (int r = 0; r < 4; r++) {
            int row = r0 + q * 4 + r;
            float s = fmaxf(acc[r] + bv, 0.f);
            __bf16 h = (__bf16)s;
            X0h[(size_t)row * 256 + col] = h;
            X0l[(size_t)row * 256 + col] = (__bf16)(s - (float)h);
        }
        return;
    }

    int t = bid - FC1_BLOCKS;
    int mode, i;
    if (t < NN)          { mode = 2; i = t; }
    else if (t < 2 * NN) { mode = 0; i = t - NN; }
    else                 { mode = 1; i = t - 2 * NN; }

    mcols += (size_t)mode * NN * MAXR;
    mvals += (size_t)mode * NN * MAXR;
    mcnt  += (size_t)mode * NN;
    db    += (size_t)mode * NN;
    int ni = cnt[i], base = i * MAXR;
    float thr = *thrp;
    float di = dvec[i];

    if (mode < 2) {
        if (tid == 0) lcnt = 0;
        __syncthreads();
        float s = 0.f;
        if (tid < ni) {
            int j = cols[base + tid];
            float a = vals[base + tid];
            float m = (mode == 0) ? a : a * di * dvec[j];
            if (m > thr) {
                int p = atomicAdd(&lcnt, 1);
                mcols[base + p] = j;
                mvals[base + p] = a;
                s = a;
            }
        }
        ds[tid] = s; __syncthreads();
        for (int off = 128; off; off >>= 1) {
            if (tid < off) ds[tid] += ds[tid + off];
            __syncthreads();
        }
        if (tid == 0) {
            mcnt[i] = lcnt;
            db[i] = 1.0f / sqrtf(ds[0] + 1.0f);
        }
        return;
    }

    if (tid == 0) { osum = 0.f; lcnt = 0; }
    for (int j = tid; j < NN; j += 256) ds[j] = 0.f;
    __syncthreads();
    for (int t2 = tid; t2 < ni; t2 += 256) {
        int j = cols[base + t2];
        float a = vals[base + t2];
        lcols[t2] = j; lvals[t2] = a;
        ds[j] = a * dvec[j] * dvec[j];
    }
    __syncthreads();
    int lane = tid & 63, wv = tid >> 6;
    int sub = lane & 15, dg = lane >> 4;      // 16-lane subgroup, 4 dots/wave in flight
    for (int o = wv * 4 + dg; o < ni; o += 16) {
        int j = lcols[o];
        int nj = cnt[j], bj = j * MAXR;
        float dot = 0.f;
        for (int t2 = sub; t2 < nj; t2 += 16)
            dot += vals[bj + t2] * ds[cols[bj + t2]];
        #pragma unroll
        for (int off = 8; off; off >>= 1) dot += __shfl_xor(dot, off);
        if (sub == 0 && di * dvec[j] * dot > thr) {
            int p = atomicAdd(&lcnt, 1);
            mcols[base + p] = j;
            mvals[base + p] = lvals[o];
            atomicAdd(&osum, lvals[o]);
        }
    }
    __syncthreads();
    if (tid == 0) {
        mcnt[i] = lcnt;
        db[i] = 1.0f / sqrtf(osum + 1.0f);
    }
}

// ---- branch-batched MFMA GEMM (split-bf16): 64x64 tile, 4 waves; z = branch ----
__global__ __launch_bounds__(256) void gemm3m_k(const __bf16* __restrict__ Ah,
                                                const __bf16* __restrict__ Al,
                                                int aplane, int K,
                                                const __bf16* __restrict__ Bh,
                                                const __bf16* __restrict__ Bl,
                                                float* __restrict__ out) {
    int tid = threadIdx.x;
    int w = tid >> 6, lane = tid & 63;
    int m = lane & 15, q = lane >> 4;
    int i0 = blockIdx.x * 64, c0 = blockIdx.y * 64;
    int z = blockIdx.z;
    int rowA = i0 + w * 16 + m;
    const __bf16* ah = Ah + (size_t)z * aplane + (size_t)rowA * K + q * 8;
    const __bf16* al = Al + (size_t)z * aplane + (size_t)rowA * K + q * 8;
    const __bf16* bh0 = Bh + (size_t)z * 128 * K + (size_t)(c0 + m) * K + q * 8;
    const __bf16* bl0 = Bl + (size_t)z * 128 * K + (size_t)(c0 + m) * K + q * 8;

    f32x4 acc[4];
    #pragma unroll
    for (int ct = 0; ct < 4; ct++)
        #pragma unroll
        for (int r = 0; r < 4; r++) acc[ct][r] = 0.f;

    for (int ks = 0; ks < K; ks += 32) {
        bf16x8 a_h = *(const bf16x8*)(ah + ks);
        bf16x8 a_l = *(const bf16x8*)(al + ks);
        #pragma unroll
        for (int ct = 0; ct < 4; ct++) {
            bf16x8 b_h = *(const bf16x8*)(bh0 + (size_t)ct * 16 * K + ks);
            bf16x8 b_l = *(const bf16x8*)(bl0 + (size_t)ct * 16 * K + ks);
            acc[ct] = __builtin_amdgcn_mfma_f32_16x16x32_bf16(a_h, b_h, acc[ct], 0, 0, 0);
            acc[ct] = __builtin_amdgcn_mfma_f32_16x16x32_bf16(a_h, b_l, acc[ct], 0, 0, 0);
            acc[ct] = __builtin_amdgcn_mfma_f32_16x16x32_bf16(a_l, b_h, acc[ct], 0, 0, 0);
        }
    }
    float* outp = out + (size_t)z * NN * 128;
    int rowBase = i0 + w * 16 + q * 4;
    #pragma unroll
    for (int ct = 0; ct < 4; ct++) {
        int col = c0 + ct * 16 + m;
        #pragma unroll
        for (int r = 0; r < 4; r++)
            outp[(size_t)(rowBase + r) * 128 + col] = acc[ct][r];
    }
}

// ---- SpMM: masked CSR, float4 gather, 8-way t-parallel, 2-deep ILP ----
__global__ __launch_bounds__(256) void spmm3_k(const int* __restrict__ mcols,
                                               const float* __restrict__ mvals,
                                               const int* __restrict__ mcnt,
                                               const float* __restrict__ db,
                                               const float* __restrict__ Xin,   // [3][NN][128]
                                               const float* __restrict__ bias0,
                                               const float* __restrict__ bias1,
                                               const float* __restrict__ bias2,
                                               __bf16* __restrict__ outAh,      // [3][NN][128] bf16 or null
                                               __bf16* __restrict__ outAl,
                                               float* __restrict__ embf, int coff) {
    __shared__ float lcoef[MAXR];
    __shared__ int lj[MAXR];
    __shared__ float4 part[8][32];
    int i = blockIdx.x, tid = threadIdx.x, b = blockIdx.y;
    mcols += (size_t)b * NN * MAXR;
    mvals += (size_t)b * NN * MAXR;
    mcnt  += (size_t)b * NN;
    db    += (size_t)b * NN;
    const float* Xb = Xin + (size_t)b * NN * 128;
    const float* bias = (b == 0) ? bias0 : (b == 1) ? bias1 : bias2;
    float dbi = db[i];
    int n = mcnt[i], base = i * MAXR;
    if (tid < n) {
        int j = mcols[base + tid];
        lj[tid] = j;
        lcoef[tid] = mvals[base + tid] * dbi * db[j];
    }
    __syncthreads();
    int g = tid >> 5, c4 = (tid & 31) << 2;
    float4 acc = make_float4(0.f, 0.f, 0.f, 0.f);
    float4 acc2 = make_float4(0.f, 0.f, 0.f, 0.f);
    if (g == 0) {
        float4 x = *(const float4*)&Xb[(size_t)i * 128 + c4];
        float d2 = dbi * dbi;
        acc = make_float4(d2 * x.x, d2 * x.y, d2 * x.z, d2 * x.w);
    }
    int t = g;
    for (; t + 8 < n; t += 16) {
        float cf0 = lcoef[t];
        float4 x0 = *(const float4*)&Xb[(size_t)lj[t] * 128 + c4];
        float cf1 = lcoef[t + 8];
        float4 x1 = *(const float4*)&Xb[(size_t)lj[t + 8] * 128 + c4];
        acc.x += cf0 * x0.x; acc.y += cf0 * x0.y; acc.z += cf0 * x0.z; acc.w += cf0 * x0.w;
        acc2.x += cf1 * x1.x; acc2.y += cf1 * x1.y; acc2.z += cf1 * x1.z; acc2.w += cf1 * x1.w;
    }
    if (t < n) {
        float cf = lcoef[t];
        float4 x = *(const float4*)&Xb[(size_t)lj[t] * 128 + c4];
        acc.x += cf * x.x; acc.y += cf * x.y; acc.z += cf * x.z; acc.w += cf * x.w;
    }
    acc.x += acc2.x; acc.y += acc2.y; acc.z += acc2.z; acc.w += acc2.w;
    part[g][tid & 31] = acc;
    __syncthreads();
    if (tid < 32) {
        float4 s = part[0][tid];
        #pragma unroll
        for (int gg = 1; gg < 8; gg++) {
            float4 t4 = part[gg][tid];
            s.x += t4.x; s.y += t4.y; s.z += t4.z; s.w += t4.w;
        }
        int cc = tid << 2;
        float4 bv = *(const float4*)&bias[cc];
        s.x = fmaxf(s.x + bv.x, 0.f); s.y = fmaxf(s.y + bv.y, 0.f);
        s.z = fmaxf(s.z + bv.z, 0.f); s.w = fmaxf(s.w + bv.w, 0.f);
        if (outAh) {
            __bf16 h0 = (__bf16)s.x, h1 = (__bf16)s.y, h2 = (__bf16)s.z, h3 = (__bf16)s.w;
            bf16x4 hv = {h0, h1, h2, h3};
            bf16x4 lv = {(__bf16)(s.x - (float)h0), (__bf16)(s.y - (float)h1),
                         (__bf16)(s.z - (float)h2), (__bf16)(s.w - (float)h3)};
            *(bf16x4*)(outAh + ((size_t)b * NN + i) * 128 + cc) = hv;
            *(bf16x4*)(outAl + ((size_t)b * NN + i) * 128 + cc) = lv;
        }
        *(float4*)&embf[((size_t)b * NN + i) * 256 + coff + cc] = s;
    }
}

// ---- dilated 3x3 conv: LDS-staged rows + split-bf16 emb for downstream MFMA ----
__global__ __launch_bounds__(256) void conv3f_k(const float* __restrict__ emb,
                                                const float* __restrict__ ck,
                                                const float* __restrict__ cb,
                                                float* __restrict__ outf,
                                                __bf16* __restrict__ embh,
                                                __bf16* __restrict__ embl) {
    __shared__ float rows[3][3][256];
    int n = blockIdx.x, c = threadIdx.x;
    #pragma unroll
    for (int i = 0; i < 3; i++)
        #pragma unroll
        for (int kh = 0; kh < 3; kh++) {
            int nn2 = n + 2 * kh - 2;
            rows[i][kh][c] = (nn2 >= 0 && nn2 < NN) ? emb[((size_t)i * NN + nn2) * 256 + c] : 0.f;
        }
    __syncthreads();
    float s = cb[0];
    #pragma unroll
    for (int i = 0; i < 3; i++)
        #pragma unroll
        for (int kh = 0; kh < 3; kh++)
            #pragma unroll
            for (int kw = 0; kw < 3; kw++) {
                int cc = c + 2 * kw - 2;
                if (cc >= 0 && cc < 256)
                    s += rows[i][kh][cc] * ck[(i * 3 + kh) * 3 + kw];
            }
    size_t idx = (size_t)n * 256 + c;
    outf[idx] = s;
    __bf16 h = (__bf16)s;
    embh[idx] = h;
    embl[idx] = (__bf16)(s - (float)h);
}

// ---- uv GEMM (MFMA split-bf16): single plane, full K=256 ----
__global__ __launch_bounds__(256) void gemmuvm_k(const __bf16* __restrict__ Ah,
                                                 const __bf16* __restrict__ Al,
                                                 const __bf16* __restrict__ Bh,
                                                 const __bf16* __restrict__ Bl,
                                                 float* __restrict__ uvp) {
    int tid = threadIdx.x;
    int w = tid >> 6, lane = tid & 63;
    int m = lane & 15, q = lane >> 4;
    int i0 = blockIdx.x * 64, c0 = blockIdx.y * 64;
    int rowA = i0 + w * 16 + m;
    const __bf16* ah = Ah + (size_t)rowA * 256 + q * 8;
    const __bf16* al = Al + (size_t)rowA * 256 + q * 8;
    const __bf16* bh0 = Bh + (size_t)(c0 + m) * 256 + q * 8;
    const __bf16* bl0 = Bl + (size_t)(c0 + m) * 256 + q * 8;

    f32x4 acc[4];
    #pragma unroll
    for (int ct = 0; ct < 4; ct++)
        #pragma unroll
        for (int r = 0; r < 4; r++) acc[ct][r] = 0.f;

    for (int ks = 0; ks < 256; ks += 32) {
        bf16x8 a_h = *(const bf16x8*)(ah + ks);
        bf16x8 a_l = *(const bf16x8*)(al + ks);
        #pragma unroll
        for (int ct = 0; ct < 4; ct++) {
            bf16x8 b_h = *(const bf16x8*)(bh0 + (size_t)ct * 16 * 256 + ks);
            bf16x8 b_l = *(const bf16x8*)(bl0 + (size_t)ct * 16 * 256 + ks);
            acc[ct] = __builtin_amdgcn_mfma_f32_16x16x32_bf16(a_h, b_h, acc[ct], 0, 0, 0);
            acc[ct] = __builtin_amdgcn_mfma_f32_16x16x32_bf16(a_h, b_l, acc[ct], 0, 0, 0);
            acc[ct] = __builtin_amdgcn_mfma_f32_16x16x32_bf16(a_l, b_h, acc[ct], 0, 0, 0);
        }
    }
    int rowBase = i0 + w * 16 + q * 4;
    #pragma unroll
    for (int ct = 0; ct < 4; ct++) {
        int col = c0 + ct * 16 + m;
        #pragma unroll
        for (int r = 0; r < 4; r++)
            uvp[(size_t)(rowBase + r) * 128 + col] = acc[ct][r];
    }
}

// ---- pair gather + logits: 16 pairs/block, 4 per wave ----
__global__ __launch_bounds__(256) void pairuv_k(const int* __restrict__ left,
                                                const int* __restrict__ right,
                                                const float* __restrict__ uvp,
                                                const float* __restrict__ ba,
                                                const float* __restrict__ Wb,
                                                const float* __restrict__ bb,
                                                float* __restrict__ out) {
    int tid = threadIdx.x;
    int w = tid >> 6, c = tid & 63;
    int base = blockIdx.x * 16 + w * 4;
    float bac = ba[c];
    float w0 = Wb[c * 2], w1 = Wb[c * 2 + 1];
    float b0 = bb[0], b1 = bb[1];
    #pragma unroll
    for (int pp = 0; pp < 4; pp++) {
        int row = base + pp;
        int l = left[row], r = right[row];
        float h = uvp[(size_t)l * 128 + c] + uvp[(size_t)r * 128 + 64 + c] + bac;
        h = fmaxf(h, 0.f);
        float s0 = h * w0, s1 = h * w1;
        for (int off = 32; off; off >>= 1) {
            s0 += __shfl_xor(s0, off);
            s1 += __shfl_xor(s1, off);
        }
        if (c == 0) {
            out[row * 2]     = s0 + b0;
            out[row * 2 + 1] = s1 + b1;
        }
    }
}

extern "C" void kernel_launch(void* const* d_in, const int* in_sizes, int n_in,
                              void* d_out, int out_size, void* d_ws, size_t ws_size,
                              hipStream_t stream) {
    const int* left  = (const int*)d_in[0];
    const int* right = (const int*)d_in[1];
    const float* X    = (const float*)d_in[2];
    const float* adj  = (const float*)d_in[3];
    const float* thr  = (const float*)d_in[4];
    const float* Wfc1 = (const float*)d_in[5];
    const float* bfc1 = (const float*)d_in[6];
    // channel order b0,b1,b2 = (adj mask, Wg5/6), (An mask, Wg3/4), (An^2 mask, Wg1/2)
    const float* Wga[3] = { (const float*)d_in[15], (const float*)d_in[11], (const float*)d_in[7] };
    const float* bga[3] = { (const float*)d_in[16], (const float*)d_in[12], (const float*)d_in[8] };
    const float* Wgb[3] = { (const float*)d_in[17], (const float*)d_in[13], (const float*)d_in[9] };
    const float* bgb[3] = { (const float*)d_in[18], (const float*)d_in[14], (const float*)d_in[10] };
    const float* cnnk = (const float*)d_in[19];
    const float* cnnb = (const float*)d_in[20];
    const float* Wa_  = (const float*)d_in[21];
    const float* ba_  = (const float*)d_in[22];
    const float* Wb_  = (const float*)d_in[23];
    const float* bb_  = (const float*)d_in[24];

    char* p = (char*)d_ws;
    auto take = [&](size_t n) { char* q = p; p += (n + 255) & ~(size_t)255; return q; };
    float* dvec = (float*)take(NN * 4);
    float* db3  = (float*)take((size_t)3 * NN * 4);
    int*   cnt  = (int*)take(NN * 4);
    int*   mcnt3 = (int*)take((size_t)3 * NN * 4);
    int*   cols = (int*)take((size_t)NN * MAXR * 4);
    float* vals = (float*)take((size_t)NN * MAXR * 4);
    int*   mcols3 = (int*)take((size_t)3 * NN * MAXR * 4);    // 7.1 MB
    float* mvals3 = (float*)take((size_t)3 * NN * MAXR * 4);  // 7.1 MB
    __bf16* X0h  = (__bf16*)take((size_t)NN * 256 * 2);
    __bf16* X0l  = (__bf16*)take((size_t)NN * 256 * 2);
    float* XWall = (float*)take((size_t)3 * NN * 128 * 4);
    __bf16* e1h  = (__bf16*)take((size_t)3 * NN * 128 * 2);
    __bf16* e1l  = (__bf16*)take((size_t)3 * NN * 128 * 2);
    float* HW2all= (float*)take((size_t)3 * NN * 128 * 4);
    float* embf  = (float*)take((size_t)3 * NN * 256 * 4);
    __bf16* Xh   = (__bf16*)take((size_t)NN * KP * 2);        // 9.6 MB (own buffer: masks run
    __bf16* Xl   = (__bf16*)take((size_t)NN * KP * 2);        //  concurrently with fc1)
    __bf16* WhT  = (__bf16*)take((size_t)256 * KP * 2);       // 0.8 MB
    __bf16* WlT  = (__bf16*)take((size_t)256 * KP * 2);       // 0.8 MB
    __bf16* WgaTh = (__bf16*)take((size_t)3 * 128 * 256 * 2);
    __bf16* WgaTl = (__bf16*)take((size_t)3 * 128 * 256 * 2);
    __bf16* WgbTh = (__bf16*)take((size_t)3 * 128 * 128 * 2);
    __bf16* WgbTl = (__bf16*)take((size_t)3 * 128 * 128 * 2);
    __bf16* WaTh  = (__bf16*)take((size_t)128 * 256 * 2);
    __bf16* WaTl  = (__bf16*)take((size_t)128 * 256 * 2);
    __bf16* embh  = (__bf16*)take((size_t)NN * 256 * 2);
    __bf16* embl  = (__bf16*)take((size_t)NN * 256 * 2);
    float* uvp   = (float*)take((size_t)NN * 128 * 4);        // 1.5 MB single plane

    float* out_logits = (float*)d_out;
    float* out_emb = out_logits + 32768;

    // fused prep: xsplit + wsplit + Wg/Wa transpose-split + csr build
    prep_k<<<XS4_BLOCKS + WSPLIT_BLOCKS + WG_BLOCKS + CSR_BLOCKS, 256, 0, stream>>>(
        adj, cols, vals, cnt, dvec, X, Xh, Xl, Wfc1, WhT, WlT,
        Wga[0], Wga[1], Wga[2], Wgb[0], Wgb[1], Wgb[2], Wa_,
        WgaTh, WgaTl, WgbTh, WgbTl, WaTh, WaTl);

    // fused: fc1 (768 short full-K tiles -> X0 h/l direct) overlapped with all masks
    fc1mask_k<<<FC1_BLOCKS + 3 * NN, 256, 0, stream>>>(cols, vals, cnt, dvec, thr,
                                                       mcols3, mvals3, mcnt3, db3,
                                                       Xh, Xl, WhT, WlT, bfc1, X0h, X0l);

    // XW[b] = X0 @ Wga[b]  (MFMA split-bf16)
    gemm3m_k<<<dim3(NN / 64, 2, 3), 256, 0, stream>>>(X0h, X0l, 0, 256, WgaTh, WgaTl, XWall);
    // e1[b] = relu(An_b @ XW[b] + bga[b]) -> e1 split-bf16 + embf cols 0..127
    spmm3_k<<<dim3(NN, 3), 256, 0, stream>>>(mcols3, mvals3, mcnt3, db3, XWall,
                                             bga[0], bga[1], bga[2], e1h, e1l, embf, 0);
    // HW2[b] = e1[b] @ Wgb[b]  (MFMA split-bf16)
    gemm3m_k<<<dim3(NN / 64, 2, 3), 256, 0, stream>>>(e1h, e1l, NN * 128, 128, WgbTh, WgbTl, HW2all);
    // e2[b] = relu(An_b @ HW2[b] + bgb[b]) -> embf cols 128..255
    spmm3_k<<<dim3(NN, 3), 256, 0, stream>>>(mcols3, mvals3, mcnt3, db3, HW2all,
                                             bgb[0], bgb[1], bgb[2], (__bf16*)0, (__bf16*)0, embf, 128);

    conv3f_k<<<NN, 256, 0, stream>>>(embf, cnnk, cnnb, out_emb, embh, embl);
    // pair MLP via u/v decomposition: uv = emb_all @ [Wa_left | Wa_right] (MFMA, full K)
    gemmuvm_k<<<dim3(NN / 64, 2), 256, 0, stream>>>(embh, embl, WaTh, WaTl, uvp);
    pairuv_k<<<16384 / 16, 256, 0, stream>>>(left, right, uvp, ba_, Wb_, bb_, out_logits);
}